// Round 1
// baseline (65.586 us; speedup 1.0000x reference)
//
#include <hip/hip_runtime.h>

// IntervalTimeEncoder: out[b,l,e] = W[e, idx(b,l)] + bias[e]
// idx(b,l) = clamp(trunc((ts[b,l]-ts[b,l-1]) / 100000.0f * 100.0f), 0, 100), idx(b,0)=0
//
// Inputs (setup_inputs order):
//   d_in[0] = inputs    int64  [128,4096]   (UNUSED by reference)
//   d_in[1] = timestamp f32    [128,4096]
//   d_in[2] = W         f32    [128,101]
//   d_in[3] = b         f32    [128]
// Output: f32 [128,4096,128] = 256 MiB  -> pure write-streaming kernel.

#define NBINS      100
#define EMB        128
#define LLEN       4096
#define TABLE_ELTS ((NBINS + 1) * EMB)   // 12928 floats = 51712 B

// Build fused table[k][e] = W[e*101 + k] + bias[e]  (transpose + bias once)
__global__ void build_table_kernel(const float* __restrict__ W,
                                   const float* __restrict__ bias,
                                   float* __restrict__ table) {
    int i = blockIdx.x * blockDim.x + threadIdx.x;
    if (i < TABLE_ELTS) {
        int k = i >> 7;       // bucket id 0..100
        int e = i & (EMB - 1);
        table[i] = W[e * (NBINS + 1) + k] + bias[e];
    }
}

// One 32-lane group per output row (128 floats = 32 float4).
// Block = 256 threads = 8 rows/step; 8 consecutive rows => 4 KB contiguous store.
__global__ __launch_bounds__(256)
void encode_kernel(const float* __restrict__ ts,
                   const float* __restrict__ table,
                   float4* __restrict__ out,
                   int nrows) {
    const int lane  = threadIdx.x & 31;
    const int group = threadIdx.x >> 5;          // 0..7
    const int step  = gridDim.x * 8;
    const float4* __restrict__ tbl4 = (const float4*)table;

    for (int row = blockIdx.x * 8 + group; row < nrows; row += step) {
        const int li = row & (LLEN - 1);
        // pass_time: 0 for first element of each row, else adjacent diff.
        float pass = 0.0f;
        if (li != 0) pass = ts[row] - ts[row - 1];   // broadcast loads (same addr per group)
        // EXACTLY the reference arithmetic: (pass / T * N) -> trunc toward 0 -> clamp
        int raw = (int)(pass / 100000.0f * 100.0f);
        raw = raw < 0 ? 0 : raw;
        raw = raw > NBINS ? NBINS : raw;

        float4 v = tbl4[raw * (EMB / 4) + lane];      // 512 B row, L1-hot
        out[(size_t)row * (EMB / 4) + lane] = v;      // coalesced streaming store
    }
}

extern "C" void kernel_launch(void* const* d_in, const int* in_sizes, int n_in,
                              void* d_out, int out_size, void* d_ws, size_t ws_size,
                              hipStream_t stream) {
    const float* ts   = (const float*)d_in[1];
    const float* W    = (const float*)d_in[2];
    const float* bias = (const float*)d_in[3];
    float* out        = (float*)d_out;
    float* table      = (float*)d_ws;               // 51712 B scratch

    // 1) Fused transpose+bias table.
    build_table_kernel<<<(TABLE_ELTS + 255) / 256, 256, 0, stream>>>(W, bias, table);

    // 2) Streaming gather-write.
    const int nrows = 128 * LLEN;                   // 524288
    const int grid  = 2048;                         // memory-bound cap, grid-stride
    encode_kernel<<<grid, 256, 0, stream>>>(ts, table, (float4*)out, nrows);
}

// Round 2
// 49.659 us; speedup vs baseline: 1.3207x; 1.3207x over previous
//
#include <hip/hip_runtime.h>

// IntervalTimeEncoder: out[b,l,e] = W[e, idx(b,l)] + bias[e]
// idx(b,l) = clamp(trunc((ts[b,l]-ts[b,l-1]) / 100000.0f * 100.0f), 0, 100), idx(b,0)=0
//
// Inputs (setup_inputs order):
//   d_in[0] = inputs    int64  [128,4096]   (UNUSED by reference)
//   d_in[1] = timestamp f32    [128,4096]
//   d_in[2] = W         f32    [128,101]
//   d_in[3] = b         f32    [128]
// Output: f32 [128,4096,128] = 256 MiB -> write-streaming bound (~38 us @ 7 TB/s).
//
// Round 2: split bucket computation (prep kernel, writes uchar idx to d_ws)
// from the streaming gather (4 independent load->store chains per group-iter)
// so the hot kernel has no IEEE-div dependency chain ahead of each store.

#define NBINS      100
#define EMB        128
#define LLEN       4096
#define NROWS      (128 * LLEN)            // 524288
#define TABLE_ELTS ((NBINS + 1) * EMB)     // 12928 floats = 51712 B
#define IDX_OFF    65536                   // byte offset of idx[] inside d_ws
#define WS_NEEDED  (IDX_OFF + NROWS)       // 65536 + 524288 bytes

__device__ __forceinline__ int bucket(float pass) {
    // EXACT reference arithmetic: f32 div, f32 mul, trunc toward 0, clamp.
    float r = pass / 100000.0f * 100.0f;
    int v = (int)r;
    v = v < 0 ? 0 : v;
    v = v > NBINS ? NBINS : v;
    return v;
}

// Fused prep: blocks [0,512) compute idx (4 rows/thread, 512*256*4 = 524288);
// blocks [512, 512+51) build table[k][e] = W[e*101+k] + bias[e].
__global__ __launch_bounds__(256)
void prep_kernel(const float* __restrict__ ts,
                 const float* __restrict__ W,
                 const float* __restrict__ bias,
                 float* __restrict__ table,
                 unsigned char* __restrict__ idx) {
    const int b = blockIdx.x;
    if (b < 512) {
        const int r0 = (b * 256 + threadIdx.x) * 4;
        float4 t = *(const float4*)&ts[r0];
        // Only row r0 can be a sequence start (r0 % 4 == 0, LLEN % 4 == 0).
        float p0 = 0.0f;
        if ((r0 & (LLEN - 1)) != 0) p0 = t.x - ts[r0 - 1];
        float p1 = t.y - t.x;
        float p2 = t.z - t.y;
        float p3 = t.w - t.z;
        uchar4 q;
        q.x = (unsigned char)bucket(p0);
        q.y = (unsigned char)bucket(p1);
        q.z = (unsigned char)bucket(p2);
        q.w = (unsigned char)bucket(p3);
        *(uchar4*)&idx[r0] = q;
    } else {
        const int i = (b - 512) * 256 + threadIdx.x;
        if (i < TABLE_ELTS) {
            int k = i >> 7;            // bucket 0..100
            int e = i & (EMB - 1);
            table[i] = W[e * (NBINS + 1) + k] + bias[e];
        }
    }
}

// Streaming gather: 32 lanes per row, 4 rows per group-iteration.
// Block = 8 groups -> 32 consecutive rows = 16 KB contiguous per iteration.
__global__ __launch_bounds__(256)
void gather_kernel(const unsigned char* __restrict__ idx,
                   const float4* __restrict__ tbl4,
                   float4* __restrict__ out) {
    const int lane  = threadIdx.x & 31;
    const int group = threadIdx.x >> 5;
    const int step  = gridDim.x * 32;
    for (int base = blockIdx.x * 32; base < NROWS; base += step) {
        const int r0 = base + group * 4;
        uchar4 q = *(const uchar4*)&idx[r0];         // broadcast load
        float4 v0 = tbl4[q.x * (EMB / 4) + lane];    // 4 independent L1-hot loads
        float4 v1 = tbl4[q.y * (EMB / 4) + lane];
        float4 v2 = tbl4[q.z * (EMB / 4) + lane];
        float4 v3 = tbl4[q.w * (EMB / 4) + lane];
        size_t o = (size_t)r0 * (EMB / 4) + lane;
        out[o]      = v0;                            // 4 independent streaming stores
        out[o + 32] = v1;
        out[o + 64] = v2;
        out[o + 96] = v3;
    }
}

// ---- Fallback (round-1 monolithic path) if ws_size is too small ----
__global__ void build_table_kernel(const float* __restrict__ W,
                                   const float* __restrict__ bias,
                                   float* __restrict__ table) {
    int i = blockIdx.x * blockDim.x + threadIdx.x;
    if (i < TABLE_ELTS) {
        int k = i >> 7;
        int e = i & (EMB - 1);
        table[i] = W[e * (NBINS + 1) + k] + bias[e];
    }
}

__global__ __launch_bounds__(256)
void encode_kernel(const float* __restrict__ ts,
                   const float* __restrict__ table,
                   float4* __restrict__ out,
                   int nrows) {
    const int lane  = threadIdx.x & 31;
    const int group = threadIdx.x >> 5;
    const int step  = gridDim.x * 8;
    const float4* __restrict__ tbl4 = (const float4*)table;
    for (int row = blockIdx.x * 8 + group; row < nrows; row += step) {
        const int li = row & (LLEN - 1);
        float pass = 0.0f;
        if (li != 0) pass = ts[row] - ts[row - 1];
        int raw = bucket(pass);
        float4 v = tbl4[raw * (EMB / 4) + lane];
        out[(size_t)row * (EMB / 4) + lane] = v;
    }
}

extern "C" void kernel_launch(void* const* d_in, const int* in_sizes, int n_in,
                              void* d_out, int out_size, void* d_ws, size_t ws_size,
                              hipStream_t stream) {
    const float* ts   = (const float*)d_in[1];
    const float* W    = (const float*)d_in[2];
    const float* bias = (const float*)d_in[3];
    float* out        = (float*)d_out;
    float* table      = (float*)d_ws;

    if (ws_size >= (size_t)WS_NEEDED) {
        unsigned char* idx = (unsigned char*)d_ws + IDX_OFF;
        // 512 idx blocks + 51 table blocks, fused into one dispatch.
        prep_kernel<<<512 + 51, 256, 0, stream>>>(ts, W, bias, table, idx);
        gather_kernel<<<2048, 256, 0, stream>>>(idx, (const float4*)table,
                                                (float4*)out);
    } else {
        build_table_kernel<<<(TABLE_ELTS + 255) / 256, 256, 0, stream>>>(W, bias, table);
        encode_kernel<<<2048, 256, 0, stream>>>(ts, table, (float4*)out, NROWS);
    }
}

// Round 3
// 46.390 us; speedup vs baseline: 1.4138x; 1.0705x over previous
//
#include <hip/hip_runtime.h>

// IntervalTimeEncoder: out[b,l,e] = W[e, idx(b,l)] + bias[e]
// idx(b,l) = clamp(trunc((ts[b,l]-ts[b,l-1]) / 100000.0f * 100.0f), 0, 100), idx(b,0)=0
//
// Inputs (setup_inputs order):
//   d_in[0] = inputs    int64  [128,4096]   (UNUSED by reference)
//   d_in[1] = timestamp f32    [128,4096]
//   d_in[2] = W         f32    [128,101]
//   d_in[3] = b         f32    [128]
// Output: f32 [128,4096,128] = 256 MiB -> write-streaming bound (~38 us @ 7 TB/s fill rate).
//
// Round 3: SINGLE kernel. Data property: gaps <= 3000 => pass/1000 <= ~3.0005
// => idx in {0,1,2,3} always (idx 0 at row starts; f32 cumsum rounding can
// nudge a diff just past 3000, giving 3). Each block builds the 4 hot fused
// table rows (2 KB: tbl[k][e] = W[e][k]+b[e]) in LDS, then streams:
// float4 ts load -> 4 independent div/trunc/clamp -> 4 ds_read_b128 ->
// 4 independent float4 stores. Cold (never-taken) W-direct path keeps
// correctness for idx > 3.

#define NBINS  100
#define EMB    128
#define LLEN   4096
#define NROWS  (128 * LLEN)            // 524288

__device__ __forceinline__ int bucket(float pass) {
    // EXACT reference arithmetic: f32 div, f32 mul, trunc toward 0, clamp.
    float r = pass / 100000.0f * 100.0f;
    int v = (int)r;
    v = v < 0 ? 0 : v;
    v = v > NBINS ? NBINS : v;
    return v;
}

__global__ __launch_bounds__(256)
void fused_encode_kernel(const float* __restrict__ ts,
                         const float* __restrict__ W,
                         const float* __restrict__ bias,
                         float4* __restrict__ out) {
    // Hot fused table rows 0..3: tbl[k*128+e] = W[e*101+k] + bias[e]  (2 KB)
    __shared__ float tbl[4 * EMB];
    for (int i = threadIdx.x; i < 4 * EMB; i += 256) {
        const int k = i >> 7;                 // 0..3
        const int e = i & (EMB - 1);
        tbl[i] = W[e * (NBINS + 1) + k] + bias[e];
    }
    __syncthreads();

    const int lane  = threadIdx.x & 31;       // float4 slot within a row
    const int group = threadIdx.x >> 5;       // 0..7, 4 rows each
    const int step  = gridDim.x * 32;
    const float4* __restrict__ t4 = (const float4*)tbl;

    for (int base = blockIdx.x * 32; base < NROWS; base += step) {
        const int r0 = base + group * 4;
        float4 t   = *(const float4*)&ts[r0];              // broadcast within group
        float prev = ts[r0 == 0 ? 0 : r0 - 1];             // broadcast
        // Row r0 is the only possible sequence start in this quad (LLEN%4==0).
        float p0 = (r0 & (LLEN - 1)) ? t.x - prev : 0.0f;
        const int q0 = bucket(p0);
        const int q1 = bucket(t.y - t.x);
        const int q2 = bucket(t.z - t.y);
        const int q3 = bucket(t.w - t.z);

        const size_t o = (size_t)r0 * (EMB / 4) + lane;
        if ((q0 | q1 | q2 | q3) < 4) {
            // Fast path (always, in practice). Group-uniform branch.
            float4 v0 = t4[q0 * (EMB / 4) + lane];          // LDS, conflict-free
            float4 v1 = t4[q1 * (EMB / 4) + lane];
            float4 v2 = t4[q2 * (EMB / 4) + lane];
            float4 v3 = t4[q3 * (EMB / 4) + lane];
            out[o]      = v0;                               // 4 independent streams
            out[o + 32] = v1;
            out[o + 64] = v2;
            out[o + 96] = v3;
        } else {
            // Cold correctness path: gather straight from W (stride-101 rows).
            float4 bb = *(const float4*)&bias[lane * 4];
            const int qs[4] = {q0, q1, q2, q3};
            #pragma unroll
            for (int j = 0; j < 4; ++j) {
                const int q = qs[j];
                float4 v;
                v.x = W[(lane * 4 + 0) * (NBINS + 1) + q] + bb.x;
                v.y = W[(lane * 4 + 1) * (NBINS + 1) + q] + bb.y;
                v.z = W[(lane * 4 + 2) * (NBINS + 1) + q] + bb.z;
                v.w = W[(lane * 4 + 3) * (NBINS + 1) + q] + bb.w;
                out[o + j * 32] = v;
            }
        }
    }
}

extern "C" void kernel_launch(void* const* d_in, const int* in_sizes, int n_in,
                              void* d_out, int out_size, void* d_ws, size_t ws_size,
                              hipStream_t stream) {
    const float* ts   = (const float*)d_in[1];
    const float* W    = (const float*)d_in[2];
    const float* bias = (const float*)d_in[3];
    (void)d_ws; (void)ws_size;

    // 2048 blocks x 256 threads: 8 grid-stride iterations per thread,
    // 16 KB contiguous stores per block-iteration.
    fused_encode_kernel<<<2048, 256, 0, stream>>>(ts, W, bias, (float4*)d_out);
}